// Round 1
// baseline (388.846 us; speedup 1.0000x reference)
//
#include <hip/hip_runtime.h>

// ProjectionPursuitProbe: h' = scale * (h - P G^{-1} P^T h), G = P^T P
// B=8, S=4096, F=1024, R=64. Rows N = 32768.
//
// v2: barrier-light restructure.
//  - pp_main phase 1 loads H directly to registers (A-fragment is lane-private),
//    double-buffered; no Ha LDS, no per-chunk barriers (16 -> 0).
//  - Y/C kept in LDS as bf16 only; dot product from f32 accumulators in-register.
//  - rowsq/dot/scale via wave shuffles; exactly ONE __syncthreads in pp_main (for Wl).
//  - pp_invert: single-wave (64 threads), zero barriers in the GJ loop, emits bf16 W.
//  - pp_pack folded into pp_gram (3 launches instead of 4).

typedef __attribute__((ext_vector_type(8))) short bf16x8;
typedef __attribute__((ext_vector_type(4))) float f32x4;

#define MFMA_B16(a, b, c) __builtin_amdgcn_mfma_f32_16x16x32_bf16((a), (b), (c), 0, 0, 0)

__device__ __forceinline__ unsigned short bf16bits(float x) {
  union { float f; unsigned u; } v; v.f = x;
  return (unsigned short)((v.u + 0x7fffu + ((v.u >> 16) & 1u)) >> 16);  // RNE
}

// ---------------- K1: gram partials + pack P -> Pb (f-major bf16), Ptb (r-major bf16) ------
__global__ void pp_gram(const float* __restrict__ P, float* __restrict__ partial,
                        unsigned short* __restrict__ Ptb, unsigned short* __restrict__ Pb) {
  __shared__ float Pl[64][68];
  const int tid = threadIdx.x, ch = blockIdx.x;
  #pragma unroll
  for (int u = 0; u < 4; ++u) {
    const int f = tid >> 2, r = (tid & 3) * 16 + 4 * u;
    *(f32x4*)&Pl[f][r] = *(const f32x4*)(P + (size_t)(ch * 64 + f) * 64 + r);
  }
  __syncthreads();
  {  // Pb[f][r]: straight bf16 copy of the staged chunk
    const int f = tid >> 2, r0 = (tid & 3) * 16;
    bf16x8 w0, w1;
    #pragma unroll
    for (int j = 0; j < 8; ++j) {
      w0[j] = (short)bf16bits(Pl[f][r0 + j]);
      w1[j] = (short)bf16bits(Pl[f][r0 + 8 + j]);
    }
    *(bf16x8*)(Pb + (size_t)(ch * 64 + f) * 64 + r0) = w0;
    *(bf16x8*)(Pb + (size_t)(ch * 64 + f) * 64 + r0 + 8) = w1;
  }
  {  // Ptb[r][f]: LDS transpose, coalesced 16B stores
    const int r = tid >> 2, f0 = (tid & 3) * 16;
    bf16x8 w0, w1;
    #pragma unroll
    for (int j = 0; j < 8; ++j) {
      w0[j] = (short)bf16bits(Pl[f0 + j][r]);
      w1[j] = (short)bf16bits(Pl[f0 + 8 + j][r]);
    }
    *(bf16x8*)(Ptb + (size_t)r * 1024 + ch * 64 + f0) = w0;
    *(bf16x8*)(Ptb + (size_t)r * 1024 + ch * 64 + f0 + 8) = w1;
  }
  const int a0 = (tid >> 4) * 4, b0 = (tid & 15) * 4;
  f32x4 acc[4];
  #pragma unroll
  for (int i = 0; i < 4; ++i) acc[i] = (f32x4){0.f, 0.f, 0.f, 0.f};
  for (int k = 0; k < 64; ++k) {
    f32x4 av = *(const f32x4*)&Pl[k][a0];
    f32x4 bv = *(const f32x4*)&Pl[k][b0];
    #pragma unroll
    for (int i = 0; i < 4; ++i) acc[i] += av[i] * bv;
  }
  #pragma unroll
  for (int i = 0; i < 4; ++i)
    *(f32x4*)(partial + (size_t)ch * 4096 + (size_t)(a0 + i) * 64 + b0) = acc[i];
}

// ---------------- K2: G = sum partials; W = G^{-1} (Gauss-Jordan, SPD). 1 wave, 0 barriers.
// Intra-wave LDS ops are processed in instruction order, so read-pivot-then-write-rows
// is safe without __syncthreads. Emits W directly as bf16.
__global__ void pp_invert(const float* __restrict__ partial, unsigned short* __restrict__ Wb) {
  __shared__ float A[64][68];
  const int i = threadIdx.x;  // 64 threads = 1 wave; thread i owns row i
  #pragma unroll
  for (int c = 0; c < 16; ++c) {
    f32x4 s = (f32x4){0.f, 0.f, 0.f, 0.f};
    #pragma unroll 4
    for (int p = 0; p < 16; ++p)
      s += *(const f32x4*)(partial + (size_t)p * 4096 + (size_t)i * 64 + c * 4);
    *(f32x4*)&A[i][c * 4] = s;
  }
  __syncthreads();  // single wave: cheap; keeps init visible before the loop
  for (int k = 0; k < 64; ++k) {
    const float d = 1.0f / A[k][k];
    const float fi = A[i][k];
    #pragma unroll
    for (int c = 0; c < 16; ++c) {
      f32x4 pr = *(const f32x4*)&A[k][c * 4];   // read pivot group (broadcast)
      f32x4 cur = *(const f32x4*)&A[i][c * 4];  // read own group
      f32x4 res;
      #pragma unroll
      for (int e = 0; e < 4; ++e) {
        const bool isp = (c * 4 + e) == k;
        const float pv = isp ? d : pr[e] * d;
        const float cu = isp ? 0.f : cur[e];
        res[e] = (i == k) ? pv : (cu - fi * pv);
      }
      *(f32x4*)&A[i][c * 4] = res;              // write own group (after all reads of it)
    }
    __builtin_amdgcn_wave_barrier();  // scheduling fence: keep iterations ordered
  }
  #pragma unroll
  for (int c = 0; c < 8; ++c) {
    bf16x8 w;
    #pragma unroll
    for (int j = 0; j < 8; ++j) w[j] = (short)bf16bits(A[i][c * 8 + j]);
    *(bf16x8*)(Wb + (size_t)i * 64 + c * 8) = w;
  }
}

// ---------------- K3: fused main kernel, 64 rows per block, 1 barrier total ---------------
__device__ __forceinline__ void ld_chunk(const float* __restrict__ hp, int ch, f32x4* v) {
  #pragma unroll
  for (int it = 0; it < 4; ++it) {
    v[2 * it] = *(const f32x4*)(hp + ch * 128 + it * 32);
    v[2 * it + 1] = *(const f32x4*)(hp + ch * 128 + it * 32 + 4);
  }
}

__device__ __forceinline__ void comp_chunk(const f32x4* v, const unsigned short* __restrict__ bp0,
                                           int ch, f32x4* accY, float& sqacc) {
  #pragma unroll
  for (int it = 0; it < 4; ++it) {
    const f32x4 v0 = v[2 * it], v1 = v[2 * it + 1];
    sqacc += v0[0] * v0[0] + v0[1] * v0[1] + v0[2] * v0[2] + v0[3] * v0[3] +
             v1[0] * v1[0] + v1[1] * v1[1] + v1[2] * v1[2] + v1[3] * v1[3];
    bf16x8 a;
    a[0] = (short)bf16bits(v0[0]); a[1] = (short)bf16bits(v0[1]);
    a[2] = (short)bf16bits(v0[2]); a[3] = (short)bf16bits(v0[3]);
    a[4] = (short)bf16bits(v1[0]); a[5] = (short)bf16bits(v1[1]);
    a[6] = (short)bf16bits(v1[2]); a[7] = (short)bf16bits(v1[3]);
    const unsigned short* bp = bp0 + ch * 128 + it * 32;
    #pragma unroll
    for (int t = 0; t < 4; ++t) {  // B[k=f][n=r] = Ptb[r][f], k-contiguous
      bf16x8 b = *(const bf16x8*)(bp + (size_t)t * 16 * 1024);
      accY[t] = MFMA_B16(a, b, accY[t]);
    }
  }
}

__global__ __launch_bounds__(256, 2) void pp_main(
    const float* __restrict__ H, const unsigned short* __restrict__ Ptb,
    const unsigned short* __restrict__ Pb, const unsigned short* __restrict__ Wb,
    float* __restrict__ out) {
  __shared__ __align__(16) unsigned short Yl[64][72];  // Y bf16, pitch 144B (16B-aligned rows)
  __shared__ __align__(16) unsigned short Cl[64][72];  // C bf16
  __shared__ __align__(16) unsigned short Wl[64][72];  // W bf16 (symmetric)

  const int tid = threadIdx.x;
  const int lane = tid & 63, wid = tid >> 6;
  const int c16 = lane & 15, quad = lane >> 4;
  const int strip = wid * 16;
  const long row0 = (long)blockIdx.x * 64;

  // stage W (8 KB bf16) cooperatively — the ONLY cross-wave LDS dependency
  #pragma unroll
  for (int g = 0; g < 2; ++g) {
    const int u = tid + g * 256;  // 512 groups of 8 bf16
    *(bf16x8*)&Wl[u >> 3][(u & 7) * 8] = *(const bf16x8*)(Wb + (size_t)u * 8);
  }
  __syncthreads();

  // ---- phase 1: Y = H @ P, H loaded straight to registers (lane-private fragments),
  //      double-buffered so chunk k+1's loads are in flight under chunk k's MFMAs ----
  f32x4 accY[4];
  #pragma unroll
  for (int t = 0; t < 4; ++t) accY[t] = (f32x4){0.f, 0.f, 0.f, 0.f};
  float sqacc = 0.f;
  const float* hp = H + (row0 + strip + c16) * 1024 + quad * 8;
  const unsigned short* bp0 = Ptb + (size_t)c16 * 1024 + quad * 8;
  {
    f32x4 va[8], vb[8];
    ld_chunk(hp, 0, va);
    #pragma unroll
    for (int c2 = 0; c2 < 4; ++c2) {
      ld_chunk(hp, 2 * c2 + 1, vb);
      comp_chunk(va, bp0, 2 * c2, accY, sqacc);
      if (c2 < 3) ld_chunk(hp, 2 * c2 + 2, va);
      comp_chunk(vb, bp0, 2 * c2 + 1, accY, sqacc);
    }
  }

  // row sum-of-squares: lane holds partial for row strip+c16; reduce across quads
  sqacc += __shfl_xor(sqacc, 16);
  sqacc += __shfl_xor(sqacc, 32);

  // Y -> LDS as bf16 (wave-private rows; intra-wave LDS order, no barrier needed)
  #pragma unroll
  for (int t = 0; t < 4; ++t)
    #pragma unroll
    for (int r = 0; r < 4; ++r)  // D layout: col = lane&15, row = quad*4+reg
      Yl[strip + quad * 4 + r][t * 16 + c16] = bf16bits(accY[t][r]);

  // ---- phase 2: C = Y @ W (W symmetric) ----
  f32x4 accC[4];
  #pragma unroll
  for (int t = 0; t < 4; ++t) accC[t] = (f32x4){0.f, 0.f, 0.f, 0.f};
  #pragma unroll
  for (int kk = 0; kk < 2; ++kk) {
    bf16x8 a = *(const bf16x8*)&Yl[strip + c16][kk * 32 + quad * 8];
    #pragma unroll
    for (int t = 0; t < 4; ++t) {
      bf16x8 b = *(const bf16x8*)&Wl[t * 16 + c16][kk * 32 + quad * 8];
      accC[t] = MFMA_B16(a, b, accC[t]);
    }
  }

  // C -> LDS as bf16
  #pragma unroll
  for (int t = 0; t < 4; ++t)
    #pragma unroll
    for (int r = 0; r < 4; ++r)
      Cl[strip + quad * 4 + r][t * 16 + c16] = bf16bits(accC[t][r]);

  // ---- per-row dot = y.c (f32, in-register) and scale = sqrt(o2/(o2-dot)), all in-wave ----
  float sc[4]; long rg[4]; bool fs[4];
  #pragma unroll
  for (int r = 0; r < 4; ++r) {
    float dd = accY[0][r] * accC[0][r] + accY[1][r] * accC[1][r] +
               accY[2][r] * accC[2][r] + accY[3][r] * accC[3][r];
    dd += __shfl_xor(dd, 1);
    dd += __shfl_xor(dd, 2);
    dd += __shfl_xor(dd, 4);
    dd += __shfl_xor(dd, 8);              // dot for row strip+quad*4+r
    const float o2 = __shfl(sqacc, quad * 4 + r);  // o2 lives on lane (quad*4+r)
    const float n2 = fmaxf(o2 - dd, 1e-30f);
    sc[r] = sqrtf(o2 / n2);
    rg[r] = row0 + strip + quad * 4 + r;
    fs[r] = ((rg[r] & 4095) == 0);        // s == 0 rows pass through exactly
  }

  // ---- phase 3: out = (H - C @ P^T) * scale ----
  bf16x8 ca0 = *(const bf16x8*)&Cl[strip + c16][quad * 8];       // A[m][k=r], k in [0,32)
  bf16x8 ca1 = *(const bf16x8*)&Cl[strip + c16][32 + quad * 8];  // k in [32,64)
  #pragma unroll 4
  for (int ft = 0; ft < 64; ++ft) {
    const unsigned short* bp = Pb + (size_t)(ft * 16 + c16) * 64 + quad * 8;
    bf16x8 b0 = *(const bf16x8*)bp;       // B[k=r][n=f] = P[f][r], r-contiguous
    bf16x8 b1 = *(const bf16x8*)(bp + 32);
    f32x4 acc = (f32x4){0.f, 0.f, 0.f, 0.f};
    acc = MFMA_B16(ca0, b0, acc);
    acc = MFMA_B16(ca1, b1, acc);
    const int f = ft * 16 + c16;
    #pragma unroll
    for (int r = 0; r < 4; ++r) {
      const long idx = rg[r] * 1024 + f;
      const float h = H[idx];  // block-local re-read: L2/L3 hit
      out[idx] = fs[r] ? h : (h - acc[r]) * sc[r];
    }
  }
}

extern "C" void kernel_launch(void* const* d_in, const int* in_sizes, int n_in,
                              void* d_out, int out_size, void* d_ws, size_t ws_size,
                              hipStream_t stream) {
  const float* H = (const float*)d_in[0];   // 8*4096*1024 fp32
  const float* P = (const float*)d_in[1];   // 1024*64 fp32
  float* out = (float*)d_out;
  // ws layout: partialG (16*4096 f32) | Wb (4096 bf16) | Ptb (65536 bf16) | Pb (65536 bf16)
  float* partial = (float*)d_ws;
  unsigned short* Wb = (unsigned short*)(partial + 16 * 4096);
  unsigned short* Ptb = Wb + 4096;
  unsigned short* Pb = Ptb + 65536;

  pp_gram<<<16, 256, 0, stream>>>(P, partial, Ptb, Pb);
  pp_invert<<<1, 64, 0, stream>>>(partial, Wb);
  pp_main<<<512, 256, 0, stream>>>(H, Ptb, Pb, Wb, out);
}

// Round 2
// 326.285 us; speedup vs baseline: 1.1917x; 1.1917x over previous
//
#include <hip/hip_runtime.h>

// ProjectionPursuitProbe: h' = scale * (h - P G^{-1} P^T h), G = P^T P
// B=8, S=4096, F=1024, R=64. Rows N = 32768.
//
// v3: occupancy fix.
//  - pp_main: K-split. 32 rows/block, 4 waves = (2 row-strips) x (2 K-halves).
//    Grid 1024 -> 4096 waves -> 4 waves/SIMD (was 2): HBM latency fully covered.
//    kh=1 waves write f32 Y-partials to LDS; kh=0 waves reduce + phase2 + scale;
//    phase 3 split by f-half across all 4 waves. Exactly 2 barriers.
//  - pp_invert: reverted to 4-wave (256-thread) GJ — the 1-wave version was the
//    round-1 wall regression (serial chain, no latency hiding). Emits bf16 W.

typedef __attribute__((ext_vector_type(8))) short bf16x8;
typedef __attribute__((ext_vector_type(4))) float f32x4;

#define MFMA_B16(a, b, c) __builtin_amdgcn_mfma_f32_16x16x32_bf16((a), (b), (c), 0, 0, 0)

__device__ __forceinline__ unsigned short bf16bits(float x) {
  union { float f; unsigned u; } v; v.f = x;
  return (unsigned short)((v.u + 0x7fffu + ((v.u >> 16) & 1u)) >> 16);  // RNE
}

// ---------------- K1: gram partials + pack P -> Pb (f-major bf16), Ptb (r-major bf16) ------
__global__ void pp_gram(const float* __restrict__ P, float* __restrict__ partial,
                        unsigned short* __restrict__ Ptb, unsigned short* __restrict__ Pb) {
  __shared__ float Pl[64][68];
  const int tid = threadIdx.x, ch = blockIdx.x;
  #pragma unroll
  for (int u = 0; u < 4; ++u) {
    const int f = tid >> 2, r = (tid & 3) * 16 + 4 * u;
    *(f32x4*)&Pl[f][r] = *(const f32x4*)(P + (size_t)(ch * 64 + f) * 64 + r);
  }
  __syncthreads();
  {  // Pb[f][r]: straight bf16 copy of the staged chunk
    const int f = tid >> 2, r0 = (tid & 3) * 16;
    bf16x8 w0, w1;
    #pragma unroll
    for (int j = 0; j < 8; ++j) {
      w0[j] = (short)bf16bits(Pl[f][r0 + j]);
      w1[j] = (short)bf16bits(Pl[f][r0 + 8 + j]);
    }
    *(bf16x8*)(Pb + (size_t)(ch * 64 + f) * 64 + r0) = w0;
    *(bf16x8*)(Pb + (size_t)(ch * 64 + f) * 64 + r0 + 8) = w1;
  }
  {  // Ptb[r][f]: LDS transpose, coalesced 16B stores
    const int r = tid >> 2, f0 = (tid & 3) * 16;
    bf16x8 w0, w1;
    #pragma unroll
    for (int j = 0; j < 8; ++j) {
      w0[j] = (short)bf16bits(Pl[f0 + j][r]);
      w1[j] = (short)bf16bits(Pl[f0 + 8 + j][r]);
    }
    *(bf16x8*)(Ptb + (size_t)r * 1024 + ch * 64 + f0) = w0;
    *(bf16x8*)(Ptb + (size_t)r * 1024 + ch * 64 + f0 + 8) = w1;
  }
  const int a0 = (tid >> 4) * 4, b0 = (tid & 15) * 4;
  f32x4 acc[4];
  #pragma unroll
  for (int i = 0; i < 4; ++i) acc[i] = (f32x4){0.f, 0.f, 0.f, 0.f};
  for (int k = 0; k < 64; ++k) {
    f32x4 av = *(const f32x4*)&Pl[k][a0];
    f32x4 bv = *(const f32x4*)&Pl[k][b0];
    #pragma unroll
    for (int i = 0; i < 4; ++i) acc[i] += av[i] * bv;
  }
  #pragma unroll
  for (int i = 0; i < 4; ++i)
    *(f32x4*)(partial + (size_t)ch * 4096 + (size_t)(a0 + i) * 64 + b0) = acc[i];
}

// ---------------- K2: G = sum partials; W = G^{-1} (Gauss-Jordan, SPD). 4 waves. ----------
__global__ void pp_invert(const float* __restrict__ partial, unsigned short* __restrict__ Wb) {
  __shared__ float A[64][68];
  const int tid = threadIdx.x;
  const int i = tid >> 2, q16 = (tid & 3) * 16;
  #pragma unroll
  for (int u = 0; u < 4; ++u) {
    f32x4 s = (f32x4){0.f, 0.f, 0.f, 0.f};
    const int off = i * 64 + q16 + 4 * u;
    for (int p = 0; p < 16; ++p) s += *(const f32x4*)(partial + (size_t)p * 4096 + off);
    *(f32x4*)&A[i][q16 + 4 * u] = s;
  }
  __syncthreads();
  for (int k = 0; k < 64; ++k) {
    const float d = 1.0f / A[k][k];
    const float f = A[i][k];
    f32x4 prs[4], cur[4];
    #pragma unroll
    for (int u = 0; u < 4; ++u) {
      prs[u] = *(const f32x4*)&A[k][q16 + 4 * u];
      cur[u] = *(const f32x4*)&A[i][q16 + 4 * u];
    }
    __syncthreads();  // all reads done before any writes
    const int kl = k - q16;  // pivot column, local to this thread's 16-col slice
    #pragma unroll
    for (int u = 0; u < 4; ++u) {
      f32x4 pv = prs[u] * d;
      if (kl >= u * 4 && kl < u * 4 + 4) { pv[kl - u * 4] = d; cur[u][kl - u * 4] = 0.f; }
      f32x4 res = (i == k) ? pv : (cur[u] - f * pv);
      *(f32x4*)&A[i][q16 + 4 * u] = res;
    }
    __syncthreads();
  }
  {  // emit bf16 W (16 cols per thread)
    bf16x8 w0, w1;
    #pragma unroll
    for (int j = 0; j < 8; ++j) {
      w0[j] = (short)bf16bits(A[i][q16 + j]);
      w1[j] = (short)bf16bits(A[i][q16 + 8 + j]);
    }
    *(bf16x8*)(Wb + (size_t)i * 64 + q16) = w0;
    *(bf16x8*)(Wb + (size_t)i * 64 + q16 + 8) = w1;
  }
}

// ---------------- K3: fused main kernel, 32 rows/block, K-split, 2 barriers ---------------
__device__ __forceinline__ void ld_chunk(const float* __restrict__ hp, int ch, f32x4* v) {
  #pragma unroll
  for (int it = 0; it < 4; ++it) {
    v[2 * it] = *(const f32x4*)(hp + ch * 128 + it * 32);
    v[2 * it + 1] = *(const f32x4*)(hp + ch * 128 + it * 32 + 4);
  }
}

__device__ __forceinline__ void comp_chunk(const f32x4* v, const unsigned short* __restrict__ bp0,
                                           int ch, f32x4* accY, float& sqacc) {
  #pragma unroll
  for (int it = 0; it < 4; ++it) {
    const f32x4 v0 = v[2 * it], v1 = v[2 * it + 1];
    sqacc += v0[0] * v0[0] + v0[1] * v0[1] + v0[2] * v0[2] + v0[3] * v0[3] +
             v1[0] * v1[0] + v1[1] * v1[1] + v1[2] * v1[2] + v1[3] * v1[3];
    bf16x8 a;
    a[0] = (short)bf16bits(v0[0]); a[1] = (short)bf16bits(v0[1]);
    a[2] = (short)bf16bits(v0[2]); a[3] = (short)bf16bits(v0[3]);
    a[4] = (short)bf16bits(v1[0]); a[5] = (short)bf16bits(v1[1]);
    a[6] = (short)bf16bits(v1[2]); a[7] = (short)bf16bits(v1[3]);
    const unsigned short* bp = bp0 + ch * 128 + it * 32;
    #pragma unroll
    for (int t = 0; t < 4; ++t) {  // B[k=f][n=r] = Ptb[r][f], k-contiguous
      bf16x8 b = *(const bf16x8*)(bp + (size_t)t * 16 * 1024);
      accY[t] = MFMA_B16(a, b, accY[t]);
    }
  }
}

__global__ __launch_bounds__(256, 4) void pp_main(
    const float* __restrict__ H, const unsigned short* __restrict__ Ptb,
    const unsigned short* __restrict__ Pb, const unsigned short* __restrict__ Wb,
    float* __restrict__ out) {
  __shared__ __align__(16) unsigned short Yl[32][72];  // Y bf16 (rows of this block)
  __shared__ __align__(16) unsigned short Cl[32][72];  // C bf16
  __shared__ __align__(16) unsigned short Wl[64][72];  // W bf16 (symmetric)
  __shared__ float Yp[32][68];                          // f32 Y partial from kh=1 waves
  __shared__ float rs[2][32];                           // per-K-half row sum-of-squares
  __shared__ float scalev[32];

  const int tid = threadIdx.x;
  const int lane = tid & 63, wid = tid >> 6;
  const int c16 = lane & 15, quad = lane >> 4;
  const int sw = wid & 1, kh = wid >> 1;  // strip index, K-half index
  const int strip = sw * 16;
  const long row0 = (long)blockIdx.x * 32;

  // stage W (8 KB bf16): 512 groups of 8 over 256 threads
  #pragma unroll
  for (int g = 0; g < 2; ++g) {
    const int u = tid + g * 256;
    *(bf16x8*)&Wl[u >> 3][(u & 7) * 8] = *(const bf16x8*)(Wb + (size_t)u * 8);
  }

  // ---- phase 1: Y_partial = H[:, kh*512:(kh+1)*512] @ P-half, straight to registers ----
  f32x4 accY[4];
  #pragma unroll
  for (int t = 0; t < 4; ++t) accY[t] = (f32x4){0.f, 0.f, 0.f, 0.f};
  float sqacc = 0.f;
  const float* hp = H + (row0 + strip + c16) * 1024 + kh * 512 + quad * 8;
  const unsigned short* bp0 = Ptb + (size_t)c16 * 1024 + kh * 512 + quad * 8;
  {
    f32x4 va[8], vb[8];
    ld_chunk(hp, 0, va);
    ld_chunk(hp, 1, vb);
    comp_chunk(va, bp0, 0, accY, sqacc);
    ld_chunk(hp, 2, va);
    comp_chunk(vb, bp0, 1, accY, sqacc);
    ld_chunk(hp, 3, vb);
    comp_chunk(va, bp0, 2, accY, sqacc);
    comp_chunk(vb, bp0, 3, accY, sqacc);
  }

  // row sum-of-squares for this K-half: reduce across quads; lane row = strip+c16
  sqacc += __shfl_xor(sqacc, 16);
  sqacc += __shfl_xor(sqacc, 32);
  if (quad == 0) rs[kh][strip + c16] = sqacc;

  // kh=1 waves publish f32 Y partials
  if (kh) {
    #pragma unroll
    for (int t = 0; t < 4; ++t)
      #pragma unroll
      for (int r = 0; r < 4; ++r)  // D layout: col = lane&15, row = quad*4+reg
        Yp[strip + quad * 4 + r][t * 16 + c16] = accY[t][r];
  }
  __syncthreads();  // barrier 1: Yp, rs, Wl all visible

  if (kh == 0) {
    // reduce K-halves -> full Y (f32), publish bf16 Y
    #pragma unroll
    for (int t = 0; t < 4; ++t)
      #pragma unroll
      for (int r = 0; r < 4; ++r) {
        accY[t][r] += Yp[strip + quad * 4 + r][t * 16 + c16];
        Yl[strip + quad * 4 + r][t * 16 + c16] = bf16bits(accY[t][r]);
      }

    // ---- phase 2: C = Y @ W (W symmetric); Yl rows are wave-private, no barrier ----
    f32x4 accC[4];
    #pragma unroll
    for (int t = 0; t < 4; ++t) accC[t] = (f32x4){0.f, 0.f, 0.f, 0.f};
    #pragma unroll
    for (int kk = 0; kk < 2; ++kk) {
      bf16x8 a = *(const bf16x8*)&Yl[strip + c16][kk * 32 + quad * 8];
      #pragma unroll
      for (int t = 0; t < 4; ++t) {
        bf16x8 b = *(const bf16x8*)&Wl[t * 16 + c16][kk * 32 + quad * 8];
        accC[t] = MFMA_B16(a, b, accC[t]);
      }
    }
    #pragma unroll
    for (int t = 0; t < 4; ++t)
      #pragma unroll
      for (int r = 0; r < 4; ++r)
        Cl[strip + quad * 4 + r][t * 16 + c16] = bf16bits(accC[t][r]);

    // ---- per-row dot = y.c and scale = sqrt(o2/(o2-dot)), in-register ----
    #pragma unroll
    for (int r = 0; r < 4; ++r) {
      float dd = accY[0][r] * accC[0][r] + accY[1][r] * accC[1][r] +
                 accY[2][r] * accC[2][r] + accY[3][r] * accC[3][r];
      dd += __shfl_xor(dd, 1);
      dd += __shfl_xor(dd, 2);
      dd += __shfl_xor(dd, 4);
      dd += __shfl_xor(dd, 8);  // dot for row strip+quad*4+r (same on all 16 lanes)
      if (c16 == 0) {
        const int row = strip + quad * 4 + r;
        const float o2 = rs[0][row] + rs[1][row];
        const float n2 = fmaxf(o2 - dd, 1e-30f);
        scalev[row] = sqrtf(o2 / n2);
      }
    }
  }
  __syncthreads();  // barrier 2: Cl, scalev visible

  // ---- phase 3: out = (H - C @ P^T) * scale; waves split the f range by kh ----
  bf16x8 ca0 = *(const bf16x8*)&Cl[strip + c16][quad * 8];       // A[m][k=r], k in [0,32)
  bf16x8 ca1 = *(const bf16x8*)&Cl[strip + c16][32 + quad * 8];  // k in [32,64)
  float sc[4]; long rg[4]; bool fs[4];
  #pragma unroll
  for (int r = 0; r < 4; ++r) {
    const int m = strip + quad * 4 + r;
    sc[r] = scalev[m];
    rg[r] = row0 + m;
    fs[r] = ((rg[r] & 4095) == 0);  // s == 0 rows pass through exactly
  }
  #pragma unroll 4
  for (int j = 0; j < 32; ++j) {
    const int ft = kh * 32 + j;
    const unsigned short* bp = Pb + (size_t)(ft * 16 + c16) * 64 + quad * 8;
    bf16x8 b0 = *(const bf16x8*)bp;       // B[k=r][n=f] = P[f][r], r-contiguous
    bf16x8 b1 = *(const bf16x8*)(bp + 32);
    f32x4 acc = (f32x4){0.f, 0.f, 0.f, 0.f};
    acc = MFMA_B16(ca0, b0, acc);
    acc = MFMA_B16(ca1, b1, acc);
    const int f = ft * 16 + c16;
    #pragma unroll
    for (int r = 0; r < 4; ++r) {
      const long idx = rg[r] * 1024 + f;
      const float h = H[idx];  // block-local re-read: L2/L3 hit
      out[idx] = fs[r] ? h : (h - acc[r]) * sc[r];
    }
  }
}

extern "C" void kernel_launch(void* const* d_in, const int* in_sizes, int n_in,
                              void* d_out, int out_size, void* d_ws, size_t ws_size,
                              hipStream_t stream) {
  const float* H = (const float*)d_in[0];   // 8*4096*1024 fp32
  const float* P = (const float*)d_in[1];   // 1024*64 fp32
  float* out = (float*)d_out;
  // ws layout: partialG (16*4096 f32) | Wb (4096 bf16) | Ptb (65536 bf16) | Pb (65536 bf16)
  float* partial = (float*)d_ws;
  unsigned short* Wb = (unsigned short*)(partial + 16 * 4096);
  unsigned short* Ptb = Wb + 4096;
  unsigned short* Pb = Ptb + 65536;

  pp_gram<<<16, 256, 0, stream>>>(P, partial, Ptb, Pb);
  pp_invert<<<1, 256, 0, stream>>>(partial, Wb);
  pp_main<<<1024, 256, 0, stream>>>(H, Ptb, Pb, Wb, out);
}